// Round 9
// baseline (214.077 us; speedup 1.0000x reference)
//
#include <hip/hip_runtime.h>

#define B_ 8
#define N_ 1024
#define DIM_ 768
#define H_ 12
#define DH_ 64
#define M_ (B_ * N_)       // 8192
#define NQKV_ (3 * DIM_)   // 2304
#define SCL_ 0.18033688011112042f  // (1/sqrt(64)) * log2(e)

typedef unsigned short u16;
typedef unsigned int u32;
typedef __attribute__((ext_vector_type(8))) unsigned short u16x8;
typedef __attribute__((ext_vector_type(4))) unsigned short u16x4;
typedef __attribute__((ext_vector_type(8))) short bf16x8;
typedef __attribute__((ext_vector_type(4))) float f32x4;

__device__ __forceinline__ u16 f2bf(float f) {
  u32 u = __builtin_bit_cast(u32, f);
  u += 0x7fffu + ((u >> 16) & 1u);
  return (u16)(u >> 16);
}
__device__ __forceinline__ float bf2f(u16 v) {
  u32 u = ((u32)v) << 16;
  return __builtin_bit_cast(float, u);
}
__device__ __forceinline__ u32 cvtpk_bf16(float lo, float hi) {
  u32 r;
  asm("v_cvt_pk_bf16_f32 %0, %1, %2" : "=v"(r) : "v"(lo), "v"(hi));
  return r;
}
__device__ __forceinline__ void async16(const void* g, void* l) {
  __builtin_amdgcn_global_load_lds(
      (const __attribute__((address_space(1))) unsigned int*)g,
      (__attribute__((address_space(3))) unsigned int*)l, 16, 0, 0);
}
// counted waits: tile t's 4 loads retired, tiles t+1(,t+2) stay in flight
#define WAIT4_BAR()                                     \
  asm volatile("s_waitcnt vmcnt(4)" ::: "memory");      \
  __builtin_amdgcn_s_barrier();                         \
  __builtin_amdgcn_sched_barrier(0)
#define WAIT0_BAR()                                     \
  asm volatile("s_waitcnt vmcnt(0)" ::: "memory");      \
  __builtin_amdgcn_s_barrier();                         \
  __builtin_amdgcn_sched_barrier(0)
#define RING_ADV(o) (o) = ((o) == 16384) ? 0 : (o) + 8192

// ---------------- cast fp32 -> bf16, vectorized x4 ----------------
__global__ __launch_bounds__(256) void cast_bf16_k(const float* __restrict__ in,
                                                   u16* __restrict__ out, int n4) {
  int i = blockIdx.x * 256 + threadIdx.x;
  if (i >= n4) return;
  float4 v = reinterpret_cast<const float4*>(in)[i];
  u16x4 o;
  o.x = f2bf(v.x); o.y = f2bf(v.y); o.z = f2bf(v.z); o.w = f2bf(v.w);
  reinterpret_cast<u16x4*>(out)[i] = o;
}

// ---------------- GEMM K-step compute (ring offset runtime) ---------------
__device__ __forceinline__ void gemm_step(const char* lA, const char* lB,
                                          const int (&aoff)[4],
                                          const int (&boff)[4],
                                          f32x4 (&acc)[4][4]) {
  bf16x8 af[4], bfr[4];
#pragma unroll
  for (int m = 0; m < 4; ++m) af[m] = *(const bf16x8*)(lA + aoff[m]);
#pragma unroll
  for (int n = 0; n < 4; ++n) bfr[n] = *(const bf16x8*)(lB + boff[n]);
#pragma unroll
  for (int m = 0; m < 4; ++m)
#pragma unroll
    for (int n = 0; n < 4; ++n)
      acc[m][n] = __builtin_amdgcn_mfma_f32_16x16x32_bf16(af[m], bfr[n],
                                                          acc[m][n], 0, 0, 0);
}

// ---------------- C = A * B^T  (A:[M,K], B:[N,K], both bf16 row-major) -----
// 128x128 tile, BK=32, 4 waves (2x2), 4x4 16x16x32 MFMA frags.
// 3-buffer LDS ring + counted vmcnt(4): loads never drain to 0 in the loop;
// tile t+2 staged while computing tile t. XCD y-panel swizzle: each XCD owns
// 8 contiguous row-blocks (A-panel 1.6MB L2-resident), streams B once.
// VSPLIT: columns >=1536 (the V part of qkv) are written TRANSPOSED to
// vT[(b*H+h)*64+d][n] instead of the C matrix (feeds attention's V^T LDS).
template <bool OUT_BF16, bool BIAS, bool VSPLIT>
__global__ __launch_bounds__(256) void gemm_bt_k(
    const u16* __restrict__ A, const u16* __restrict__ Bm,
    void* __restrict__ Cv, const float* __restrict__ bias, int K, int ldc,
    u16* __restrict__ vT) {
  __shared__ u16 As[3][128 * 32];   // 8192 B per buffer
  __shared__ u16 Bs[3][128 * 32];
  const int t = threadIdx.x;
  const int lane = t & 63;
  const int wid = t >> 6;
  // XCD swizzle (grid is 1D, nwg = 8*8*NBX, nby=64): bijective
  const int id = blockIdx.x;
  const int xcd = id & 7, r = id >> 3;
  const int brow = ((xcd << 3) | (r & 7)) << 7;   // by = xcd*8 + (r&7)
  const int bcol = (r >> 3) << 7;                 // bx = r/8
  const int wrow = (wid >> 1) << 6;
  const int wcol = (wid & 1) << 6;

  f32x4 acc[4][4];
#pragma unroll
  for (int m = 0; m < 4; ++m)
#pragma unroll
    for (int n = 0; n < 4; ++n) acc[m][n] = (f32x4){0.f, 0.f, 0.f, 0.f};

  const int loff0 = t << 4, loff1 = (t + 256) << 4;
  const int r0 = loff0 >> 6, r1 = loff1 >> 6;
  const int s0 = ((((loff0 >> 4) & 3) ^ (r0 & 3)) << 3);
  const int s1 = ((((loff1 >> 4) & 3) ^ (r1 & 3)) << 3);
  const u16* pA0 = A + (size_t)(brow + r0) * K + s0;
  const u16* pA1 = A + (size_t)(brow + r1) * K + s1;
  const u16* pB0 = Bm + (size_t)(bcol + r0) * K + s0;
  const u16* pB1 = Bm + (size_t)(bcol + r1) * K + s1;
  char* lA = (char*)As;
  char* lB = (char*)Bs;
  int sb = 0, cb = 0;  // stage / compute ring byte offsets

#define GSTAGE()                                  \
  do {                                            \
    async16(pA0, lA + sb + loff0);                \
    async16(pA1, lA + sb + loff1);                \
    async16(pB0, lB + sb + loff0);                \
    async16(pB1, lB + sb + loff1);                \
    pA0 += 32; pA1 += 32; pB0 += 32; pB1 += 32;   \
    RING_ADV(sb);                                 \
  } while (0)

  const int kb = (lane >> 4) << 4;
  int aoff[4], boff[4];
#pragma unroll
  for (int m = 0; m < 4; ++m) {
    int ra = wrow + (m << 4) + (lane & 15);
    aoff[m] = (ra << 6) + (kb ^ ((ra & 3) << 4));
    int rb = wcol + (m << 4) + (lane & 15);
    boff[m] = (rb << 6) + (kb ^ ((rb & 3) << 4));
  }

  const int nkt = K >> 5;  // 24 for K=768
  GSTAGE();                // tile 0 -> buf0
  GSTAGE();                // tile 1 -> buf1
  for (int kt = 0; kt < nkt - 2; ++kt) {
    WAIT4_BAR();           // tile kt resident; kt+1 in flight
    GSTAGE();              // tile kt+2 (has 2 compute phases to land)
    gemm_step(lA + cb, lB + cb, aoff, boff, acc);
    RING_ADV(cb);
  }
  WAIT4_BAR();             // tile nkt-2 resident
  gemm_step(lA + cb, lB + cb, aoff, boff, acc);
  RING_ADV(cb);
  WAIT0_BAR();             // tile nkt-1 resident
  gemm_step(lA + cb, lB + cb, aoff, boff, acc);
#undef GSTAGE

  // epilogue: C/D layout col=lane&15, row=(lane>>4)*4+j  [m89/m91]
  const int crow = brow + wrow + ((lane >> 4) << 2);
  const int ccol0 = bcol + wcol + (lane & 15);
  if (VSPLIT && bcol >= 2 * DIM_) {
    // transposed V write: vT[(b*H+h)*64+d][n], 4 consecutive tokens -> 8B
#pragma unroll
    for (int n = 0; n < 4; ++n) {
      int colh = ccol0 + (n << 4) - 2 * DIM_;
      int h = colh >> 6, d = colh & 63;
#pragma unroll
      for (int m = 0; m < 4; ++m) {
        int row0 = crow + (m << 4);
        int bb = row0 >> 10, nn = row0 & 1023;
        int hbl = bb * H_ + h;
        uint2 pk;
        pk.x = (u32)f2bf(acc[m][n][0]) | ((u32)f2bf(acc[m][n][1]) << 16);
        pk.y = (u32)f2bf(acc[m][n][2]) | ((u32)f2bf(acc[m][n][3]) << 16);
        *(uint2*)(vT + (((size_t)(hbl * 64 + d)) << 10) + nn) = pk;
      }
    }
    return;
  }
#pragma unroll
  for (int m = 0; m < 4; ++m)
#pragma unroll
    for (int n = 0; n < 4; ++n) {
      int col = ccol0 + (n << 4);
      float bv = BIAS ? bias[col] : 0.f;
#pragma unroll
      for (int j = 0; j < 4; ++j) {
        int row = crow + (m << 4) + j;
        if (OUT_BF16)
          ((u16*)Cv)[(size_t)row * ldc + col] = f2bf(acc[m][n][j]);
        else
          ((float*)Cv)[(size_t)row * ldc + col] = acc[m][n][j] + bv;
      }
    }
}

// ---------------- attention tile (ring offsets runtime) -------------------
__device__ __forceinline__ void attn_tile(const char* lk, const char* lv,
                                          char* lp, const bf16x8 (&qf)[2],
                                          f32x4 (&oacc)[4], float& mrow,
                                          float& lrow, const int rowB,
                                          const int xsw, const int x0,
                                          const int x1, const int g) {
  // S^T = K Q^T : s4[n] holds S^T[kv=16n+4g+j][q=lane&15]
  f32x4 s4[4];
#pragma unroll
  for (int n = 0; n < 4; ++n) s4[n] = (f32x4){0.f, 0.f, 0.f, 0.f};
  __builtin_amdgcn_s_setprio(1);
#pragma unroll
  for (int n = 0; n < 4; ++n) {
    bf16x8 kf0 = *(const bf16x8*)(lk + (n << 11) + rowB + x0);
    s4[n] = __builtin_amdgcn_mfma_f32_16x16x32_bf16(kf0, qf[0], s4[n], 0, 0, 0);
    bf16x8 kf1 = *(const bf16x8*)(lk + (n << 11) + rowB + x1);
    s4[n] = __builtin_amdgcn_mfma_f32_16x16x32_bf16(kf1, qf[1], s4[n], 0, 0, 0);
  }
  __builtin_amdgcn_s_setprio(0);

  // tile max (tree; lanes sharing q combined via xor16/xor32)
  float mx;
  {
    float a0 = fmaxf(fmaxf(s4[0][0], s4[0][1]), fmaxf(s4[0][2], s4[0][3]));
    float a1 = fmaxf(fmaxf(s4[1][0], s4[1][1]), fmaxf(s4[1][2], s4[1][3]));
    float a2 = fmaxf(fmaxf(s4[2][0], s4[2][1]), fmaxf(s4[2][2], s4[2][3]));
    float a3 = fmaxf(fmaxf(s4[3][0], s4[3][1]), fmaxf(s4[3][2], s4[3][3]));
    mx = fmaxf(fmaxf(a0, a1), fmaxf(a2, a3));
    mx = fmaxf(mx, __shfl_xor(mx, 16, 64));
    mx = fmaxf(mx, __shfl_xor(mx, 32, 64));
  }
  // defer-max: rescale only when the running max grew by > 8 (exp2 domain)
  if (!__all(mx - mrow <= 8.f)) {
    float mn = fmaxf(mrow, mx);
    float al = __builtin_amdgcn_exp2f(mrow - mn);
    mrow = mn;
    lrow *= al;
    float alj[4];
#pragma unroll
    for (int j = 0; j < 4; ++j) alj[j] = __shfl(al, (g << 2) + j, 64);
#pragma unroll
    for (int d = 0; d < 4; ++d)
#pragma unroll
      for (int j = 0; j < 4; ++j) oacc[d][j] *= alj[j];
  }

  float p[4][4];
  float ps = 0.f;
#pragma unroll
  for (int n = 0; n < 4; ++n)
#pragma unroll
    for (int j = 0; j < 4; ++j) {
      p[n][j] = __builtin_amdgcn_exp2f(s4[n][j] - mrow);
      ps += p[n][j];
    }
  ps += __shfl_xor(ps, 16, 64);
  ps += __shfl_xor(ps, 32, 64);
  lrow += ps;

  // P -> per-wave LDS [q][kv] via cvt_pk (lane's kv=16n+4g+j at row q)
#pragma unroll
  for (int n = 0; n < 4; ++n) {
    uint2 pk;
    pk.x = cvtpk_bf16(p[n][0], p[n][1]);
    pk.y = cvtpk_bf16(p[n][2], p[n][3]);
    *(uint2*)(lp + rowB + (((n << 5) + (g << 3)) ^ xsw)) = pk;
  }

  // O += P V : A=P[q][kv] (row=q), B=V^T[d][kv] (col=d)
  bf16x8 pf0 = *(const bf16x8*)(lp + rowB + x0);
  bf16x8 pf1 = *(const bf16x8*)(lp + rowB + x1);
  __builtin_amdgcn_s_setprio(1);
#pragma unroll
  for (int dt = 0; dt < 4; ++dt) {
    bf16x8 vf0 = *(const bf16x8*)(lv + (dt << 11) + rowB + x0);
    oacc[dt] = __builtin_amdgcn_mfma_f32_16x16x32_bf16(pf0, vf0, oacc[dt], 0, 0, 0);
    bf16x8 vf1 = *(const bf16x8*)(lv + (dt << 11) + rowB + x1);
    oacc[dt] = __builtin_amdgcn_mfma_f32_16x16x32_bf16(pf1, vf1, oacc[dt], 0, 0, 0);
  }
  __builtin_amdgcn_s_setprio(0);
}

// ---------------- fused flash attention, swapped-QK^T, 3-ring -------------
// block = 4 waves, 64 Q rows (16/wave); 16 KV tiles of 64.
// 3-buffer LDS ring + counted vmcnt(4): stage t+2 while computing t; loads
// never drain to 0 inside the loop (4 always in flight across the barrier).
__global__ __launch_bounds__(256) void attn_k(const u16* __restrict__ qkv,
                                              const u16* __restrict__ vT,
                                              u16* __restrict__ ob) {
  __shared__ u16 Ks[3][64 * 64];   // [buf][kv][d] rows 128B, swz ^((kv&7)<<4)
  __shared__ u16 Vt[3][64 * 64];   // [buf][d][kv] rows 128B, swz ^((d&7)<<4)
  __shared__ u16 Ps[4][16 * 64];   // per-wave P [q][kv], swz ^((q&7)<<4)
  const int t = threadIdx.x;
  const int lane = t & 63;
  const int w = t >> 6;
  const int g = lane >> 4;
  const int q15 = lane & 15;

  // XCD-aware swizzle: 1536 blocks = 8 XCDs x 12 heads x 16 q-tiles
  const int orig = blockIdx.x;
  const int sub = orig >> 3;
  const int hb = (orig & 7) * 12 + (sub >> 4);
  const int qt = sub & 15;
  const int b = hb / H_;
  const int h = hb - b * H_;
  const int rowbase = b * N_;
  const int qcol = h * DH_;
  const int kcol = DIM_ + qcol;

  // Q fragment (B-operand: col=q15, k=d=g*8+j+32ks), pre-scaled by SCL_
  bf16x8 qf[2];
  {
    const int qrow = rowbase + (qt << 6) + (w << 4) + q15;
    const u16* src = qkv + (size_t)qrow * NQKV_ + qcol + (g << 3);
#pragma unroll
    for (int ks = 0; ks < 2; ++ks) {
      u16x8 raw = *(const u16x8*)(src + ks * 32);
      bf16x8 o;
#pragma unroll
      for (int j = 0; j < 8; ++j) o[j] = (short)f2bf(bf2f(raw[j]) * SCL_);
      qf[ks] = o;
    }
  }

  float mrow = -1e30f, lrow = 0.f;
  f32x4 oacc[4];
#pragma unroll
  for (int d = 0; d < 4; ++d) oacc[d] = (f32x4){0.f, 0.f, 0.f, 0.f};

  // staging: thread t owns LDS bytes t*16 (rows 0..31) and (t+256)*16
  // (rows 32..63); source chunk pre-swizzled: c' = c ^ (row&7)  (rule #21).
  const int sr = t >> 3;
  const int c8 = t & 7;
  const int loff0 = t << 4, loff1 = (t + 256) << 4;
  const u16* pk0 = qkv + (size_t)(rowbase + sr) * NQKV_ + kcol + ((c8 ^ (sr & 7)) << 3);
  const u16* pk1 = qkv + (size_t)(rowbase + sr + 32) * NQKV_ + kcol + ((c8 ^ (sr & 7)) << 3);
  const u16* pv0 = vT + (((size_t)(hb * 64 + sr)) << 10) + ((c8 ^ (sr & 7)) << 3);
  const u16* pv1 = vT + (((size_t)(hb * 64 + sr + 32)) << 10) + ((c8 ^ (sr & 7)) << 3);
  char* lk0 = (char*)Ks;   // ring stride 8192 B
  char* lv0 = (char*)Vt;
  char* lp = (char*)Ps + (w << 11);
  int sb = 0, cb = 0;

#define ASTAGE()                                           \
  do {                                                     \
    async16(pk0, lk0 + sb + loff0);                        \
    async16(pk1, lk0 + sb + loff1);                        \
    async16(pv0, lv0 + sb + loff0);                        \
    async16(pv1, lv0 + sb + loff1);                        \
    pk0 += (size_t)64 * NQKV_; pk1 += (size_t)64 * NQKV_;  \
    pv0 += 64; pv1 += 64;                                  \
    RING_ADV(sb);                                          \
  } while (0)

  // loop-invariant read offsets (note: kv&7 == d&7 == q15&7 across uses)
  const int rowB = q15 << 7;
  const int xsw = (q15 & 7) << 4;
  const int x0 = (g << 4) ^ xsw;
  const int x1 = (64 + (g << 4)) ^ xsw;

  ASTAGE();  // tile 0 -> buf0
  ASTAGE();  // tile 1 -> buf1
  for (int kvt = 0; kvt < 14; ++kvt) {
    WAIT4_BAR();   // tile kvt resident; kvt+1 in flight
    ASTAGE();      // tile kvt+2
    attn_tile(lk0 + cb, lv0 + cb, lp, qf, oacc, mrow, lrow, rowB, xsw, x0, x1, g);
    RING_ADV(cb);
  }
  WAIT4_BAR();     // tile 14 resident
  attn_tile(lk0 + cb, lv0 + cb, lp, qf, oacc, mrow, lrow, rowB, xsw, x0, x1, g);
  RING_ADV(cb);
  WAIT0_BAR();     // tile 15 resident
  attn_tile(lk0 + cb, lv0 + cb, lp, qf, oacc, mrow, lrow, rowB, xsw, x0, x1, g);
#undef ASTAGE

  // epilogue: normalize, write o[token][h*64+d] (bf16)
  float rl = 1.f / lrow;
  float rlj[4];
#pragma unroll
  for (int j = 0; j < 4; ++j) rlj[j] = __shfl(rl, (g << 2) + j, 64);
  const int orow0 = rowbase + (qt << 6) + (w << 4) + (g << 2);
#pragma unroll
  for (int dt = 0; dt < 4; ++dt) {
    int col = qcol + (dt << 4) + q15;
#pragma unroll
    for (int j = 0; j < 4; ++j)
      ob[(size_t)(orow0 + j) * DIM_ + col] = f2bf(oacc[dt][j] * rlj[j]);
  }
}

// ---------------- launch ----------------
extern "C" void kernel_launch(void* const* d_in, const int* in_sizes, int n_in,
                              void* d_out, int out_size, void* d_ws, size_t ws_size,
                              hipStream_t stream) {
  const float* x = (const float*)d_in[0];
  const float* w_qkv = (const float*)d_in[1];
  const float* w_out = (const float*)d_in[2];
  const float* b_out = (const float*)d_in[3];

  u16* xb = (u16*)d_ws;                               // 8192*768
  u16* wqkvb = xb + (size_t)M_ * DIM_;                // 2304*768
  u16* woutb = wqkvb + (size_t)NQKV_ * DIM_;          // 768*768
  u16* qkvb = woutb + (size_t)DIM_ * DIM_;            // 8192*2304 (V third unused)
  u16* obuf = qkvb + (size_t)M_ * NQKV_;              // 8192*768
  u16* vT = obuf + (size_t)M_ * DIM_;                 // 96*64*1024 transposed V
  // total ~80.2 MB of workspace

  {
    int n4 = M_ * DIM_ / 4;
    cast_bf16_k<<<(n4 + 255) / 256, 256, 0, stream>>>(x, xb, n4);
  }
  {
    int n4 = NQKV_ * DIM_ / 4;
    cast_bf16_k<<<(n4 + 255) / 256, 256, 0, stream>>>(w_qkv, wqkvb, n4);
  }
  {
    int n4 = DIM_ * DIM_ / 4;
    cast_bf16_k<<<(n4 + 255) / 256, 256, 0, stream>>>(w_out, woutb, n4);
  }

  // 1D grids with in-kernel XCD y-panel swizzle (nby=64=8x8 exactly)
  gemm_bt_k<true, false, true><<<dim3((NQKV_ / 128) * (M_ / 128)), 256, 0, stream>>>(
      xb, wqkvb, (void*)qkvb, nullptr, DIM_, NQKV_, vT);

  attn_k<<<dim3(B_ * H_ * 16), 256, 0, stream>>>(qkvb, vT, obuf);

  gemm_bt_k<false, true, false><<<dim3((DIM_ / 128) * (M_ / 128)), 256, 0, stream>>>(
      obuf, woutb, d_out, b_out, DIM_, DIM_, nullptr);
}

// Round 11
// 197.141 us; speedup vs baseline: 1.0859x; 1.0859x over previous
//
#include <hip/hip_runtime.h>

#define B_ 8
#define N_ 1024
#define DIM_ 768
#define H_ 12
#define DH_ 64
#define M_ (B_ * N_)       // 8192
#define NQKV_ (3 * DIM_)   // 2304
#define SCL_ 0.18033688011112042f  // (1/sqrt(64)) * log2(e)

typedef unsigned short u16;
typedef unsigned int u32;
typedef __attribute__((ext_vector_type(8))) unsigned short u16x8;
typedef __attribute__((ext_vector_type(4))) unsigned short u16x4;
typedef __attribute__((ext_vector_type(8))) short bf16x8;
typedef __attribute__((ext_vector_type(4))) float f32x4;

__device__ __forceinline__ u16 f2bf(float f) {
  u32 u = __builtin_bit_cast(u32, f);
  u += 0x7fffu + ((u >> 16) & 1u);
  return (u16)(u >> 16);
}
__device__ __forceinline__ float bf2f(u16 v) {
  u32 u = ((u32)v) << 16;
  return __builtin_bit_cast(float, u);
}
__device__ __forceinline__ u32 cvtpk_bf16(float lo, float hi) {
  u32 r;
  asm("v_cvt_pk_bf16_f32 %0, %1, %2" : "=v"(r) : "v"(lo), "v"(hi));
  return r;
}
__device__ __forceinline__ void async16(const void* g, void* l) {
  __builtin_amdgcn_global_load_lds(
      (const __attribute__((address_space(1))) unsigned int*)g,
      (__attribute__((address_space(3))) unsigned int*)l, 16, 0, 0);
}
#define WAIT4_BAR()                                     \
  asm volatile("s_waitcnt vmcnt(4)" ::: "memory");      \
  __builtin_amdgcn_s_barrier();                         \
  __builtin_amdgcn_sched_barrier(0)
#define WAIT0_BAR()                                     \
  asm volatile("s_waitcnt vmcnt(0)" ::: "memory");      \
  __builtin_amdgcn_s_barrier();                         \
  __builtin_amdgcn_sched_barrier(0)
#define RING_ADV(o) (o) = ((o) == 16384) ? 0 : (o) + 8192

// ---------------- cast fp32 -> bf16, vectorized x4 ----------------
__global__ __launch_bounds__(256) void cast_bf16_k(const float* __restrict__ in,
                                                   u16* __restrict__ out, int n4) {
  int i = blockIdx.x * 256 + threadIdx.x;
  if (i >= n4) return;
  float4 v = reinterpret_cast<const float4*>(in)[i];
  u16x4 o;
  o.x = f2bf(v.x); o.y = f2bf(v.y); o.z = f2bf(v.z); o.w = f2bf(v.w);
  reinterpret_cast<u16x4*>(out)[i] = o;
}

// ---------------- GEMM K-step compute (ring offset runtime) ---------------
__device__ __forceinline__ void gemm_step(const char* lA, const char* lB,
                                          const int (&aoff)[4],
                                          const int (&boff)[4],
                                          f32x4 (&acc)[4][4]) {
  bf16x8 af[4], bfr[4];
#pragma unroll
  for (int m = 0; m < 4; ++m) af[m] = *(const bf16x8*)(lA + aoff[m]);
#pragma unroll
  for (int n = 0; n < 4; ++n) bfr[n] = *(const bf16x8*)(lB + boff[n]);
#pragma unroll
  for (int m = 0; m < 4; ++m)
#pragma unroll
    for (int n = 0; n < 4; ++n)
      acc[m][n] = __builtin_amdgcn_mfma_f32_16x16x32_bf16(af[m], bfr[n],
                                                          acc[m][n], 0, 0, 0);
}

// ---------------- C = A * B^T  (unchanged from R9) ------------------------
// 128x128 tile, BK=32, 3-buffer ring + counted vmcnt(4), XCD y-panel swizzle.
template <bool OUT_BF16, bool BIAS, bool VSPLIT>
__global__ __launch_bounds__(256) void gemm_bt_k(
    const u16* __restrict__ A, const u16* __restrict__ Bm,
    void* __restrict__ Cv, const float* __restrict__ bias, int K, int ldc,
    u16* __restrict__ vT) {
  __shared__ u16 As[3][128 * 32];   // 8192 B per buffer
  __shared__ u16 Bs[3][128 * 32];
  const int t = threadIdx.x;
  const int lane = t & 63;
  const int wid = t >> 6;
  const int id = blockIdx.x;
  const int xcd = id & 7, r = id >> 3;
  const int brow = ((xcd << 3) | (r & 7)) << 7;   // by = xcd*8 + (r&7)
  const int bcol = (r >> 3) << 7;                 // bx = r/8
  const int wrow = (wid >> 1) << 6;
  const int wcol = (wid & 1) << 6;

  f32x4 acc[4][4];
#pragma unroll
  for (int m = 0; m < 4; ++m)
#pragma unroll
    for (int n = 0; n < 4; ++n) acc[m][n] = (f32x4){0.f, 0.f, 0.f, 0.f};

  const int loff0 = t << 4, loff1 = (t + 256) << 4;
  const int r0 = loff0 >> 6, r1 = loff1 >> 6;
  const int s0 = ((((loff0 >> 4) & 3) ^ (r0 & 3)) << 3);
  const int s1 = ((((loff1 >> 4) & 3) ^ (r1 & 3)) << 3);
  const u16* pA0 = A + (size_t)(brow + r0) * K + s0;
  const u16* pA1 = A + (size_t)(brow + r1) * K + s1;
  const u16* pB0 = Bm + (size_t)(bcol + r0) * K + s0;
  const u16* pB1 = Bm + (size_t)(bcol + r1) * K + s1;
  char* lA = (char*)As;
  char* lB = (char*)Bs;
  int sb = 0, cb = 0;  // stage / compute ring byte offsets

#define GSTAGE()                                  \
  do {                                            \
    async16(pA0, lA + sb + loff0);                \
    async16(pA1, lA + sb + loff1);                \
    async16(pB0, lB + sb + loff0);                \
    async16(pB1, lB + sb + loff1);                \
    pA0 += 32; pA1 += 32; pB0 += 32; pB1 += 32;   \
    RING_ADV(sb);                                 \
  } while (0)

  const int kb = (lane >> 4) << 4;
  int aoff[4], boff[4];
#pragma unroll
  for (int m = 0; m < 4; ++m) {
    int ra = wrow + (m << 4) + (lane & 15);
    aoff[m] = (ra << 6) + (kb ^ ((ra & 3) << 4));
    int rb = wcol + (m << 4) + (lane & 15);
    boff[m] = (rb << 6) + (kb ^ ((rb & 3) << 4));
  }

  const int nkt = K >> 5;  // 24 for K=768
  GSTAGE();                // tile 0 -> buf0
  GSTAGE();                // tile 1 -> buf1
  for (int kt = 0; kt < nkt - 2; ++kt) {
    WAIT4_BAR();           // tile kt resident; kt+1 in flight
    GSTAGE();              // tile kt+2 (has 2 compute phases to land)
    gemm_step(lA + cb, lB + cb, aoff, boff, acc);
    RING_ADV(cb);
  }
  WAIT4_BAR();             // tile nkt-2 resident
  gemm_step(lA + cb, lB + cb, aoff, boff, acc);
  RING_ADV(cb);
  WAIT0_BAR();             // tile nkt-1 resident
  gemm_step(lA + cb, lB + cb, aoff, boff, acc);
#undef GSTAGE

  // epilogue: C/D layout col=lane&15, row=(lane>>4)*4+j  [m89/m91]
  const int crow = brow + wrow + ((lane >> 4) << 2);
  const int ccol0 = bcol + wcol + (lane & 15);
  if (VSPLIT && bcol >= 2 * DIM_) {
#pragma unroll
    for (int n = 0; n < 4; ++n) {
      int colh = ccol0 + (n << 4) - 2 * DIM_;
      int h = colh >> 6, d = colh & 63;
#pragma unroll
      for (int m = 0; m < 4; ++m) {
        int row0 = crow + (m << 4);
        int bb = row0 >> 10, nn = row0 & 1023;
        int hbl = bb * H_ + h;
        uint2 pk;
        pk.x = (u32)f2bf(acc[m][n][0]) | ((u32)f2bf(acc[m][n][1]) << 16);
        pk.y = (u32)f2bf(acc[m][n][2]) | ((u32)f2bf(acc[m][n][3]) << 16);
        *(uint2*)(vT + (((size_t)(hbl * 64 + d)) << 10) + nn) = pk;
      }
    }
    return;
  }
#pragma unroll
  for (int m = 0; m < 4; ++m)
#pragma unroll
    for (int n = 0; n < 4; ++n) {
      int col = ccol0 + (n << 4);
      float bv = BIAS ? bias[col] : 0.f;
#pragma unroll
      for (int j = 0; j < 4; ++j) {
        int row = crow + (m << 4) + j;
        if (OUT_BF16)
          ((u16*)Cv)[(size_t)row * ldc + col] = f2bf(acc[m][n][j]);
        else
          ((float*)Cv)[(size_t)row * ldc + col] = acc[m][n][j] + bv;
      }
    }
}

// ---------------- attention tile (2-buffer; compile-time offsets) ---------
// lacc accumulates the softmax denominator via MFMA against a ones B-operand
// (replaces the 16-add sum tree + 2 shuffles on the VALU-contended pipe).
template <int KOFF, int VOFF>
__device__ __forceinline__ void attn_tile(const char* lk0, const char* lv0,
                                          char* lp, const bf16x8 (&qf)[2],
                                          f32x4 (&oacc)[4], f32x4& lacc,
                                          float& mrow, const int rowB,
                                          const int xsw, const int x0,
                                          const int x1, const int g) {
  // S^T = K Q^T : s4[n] holds S^T[kv=16n+4g+j][q=lane&15]
  f32x4 s4[4];
#pragma unroll
  for (int n = 0; n < 4; ++n) s4[n] = (f32x4){0.f, 0.f, 0.f, 0.f};
  __builtin_amdgcn_s_setprio(1);
#pragma unroll
  for (int n = 0; n < 4; ++n) {
    bf16x8 kf0 = *(const bf16x8*)(lk0 + KOFF + (n << 11) + rowB + x0);
    s4[n] = __builtin_amdgcn_mfma_f32_16x16x32_bf16(kf0, qf[0], s4[n], 0, 0, 0);
    bf16x8 kf1 = *(const bf16x8*)(lk0 + KOFF + (n << 11) + rowB + x1);
    s4[n] = __builtin_amdgcn_mfma_f32_16x16x32_bf16(kf1, qf[1], s4[n], 0, 0, 0);
  }
  __builtin_amdgcn_s_setprio(0);

  // tile max (tree; lanes sharing q combined via xor16/xor32)
  float mx;
  {
    float a0 = fmaxf(fmaxf(s4[0][0], s4[0][1]), fmaxf(s4[0][2], s4[0][3]));
    float a1 = fmaxf(fmaxf(s4[1][0], s4[1][1]), fmaxf(s4[1][2], s4[1][3]));
    float a2 = fmaxf(fmaxf(s4[2][0], s4[2][1]), fmaxf(s4[2][2], s4[2][3]));
    float a3 = fmaxf(fmaxf(s4[3][0], s4[3][1]), fmaxf(s4[3][2], s4[3][3]));
    mx = fmaxf(fmaxf(a0, a1), fmaxf(a2, a3));
    mx = fmaxf(mx, __shfl_xor(mx, 16, 64));
    mx = fmaxf(mx, __shfl_xor(mx, 32, 64));
  }
  // defer-max: rescale only when the running max grew by > 8 (exp2 domain).
  // lacc rescales with oacc, keeping the denominator consistent.
  if (!__all(mx - mrow <= 8.f)) {
    float mn = fmaxf(mrow, mx);
    float al = __builtin_amdgcn_exp2f(mrow - mn);
    mrow = mn;
    float alj[4];
#pragma unroll
    for (int j = 0; j < 4; ++j) alj[j] = __shfl(al, (g << 2) + j, 64);
#pragma unroll
    for (int j = 0; j < 4; ++j) lacc[j] *= alj[j];
#pragma unroll
    for (int d = 0; d < 4; ++d)
#pragma unroll
      for (int j = 0; j < 4; ++j) oacc[d][j] *= alj[j];
  }

  float p[4][4];
#pragma unroll
  for (int n = 0; n < 4; ++n)
#pragma unroll
    for (int j = 0; j < 4; ++j)
      p[n][j] = __builtin_amdgcn_exp2f(s4[n][j] - mrow);

  // P -> per-wave LDS [q][kv] via cvt_pk (lane's kv=16n+4g+j at row q)
#pragma unroll
  for (int n = 0; n < 4; ++n) {
    uint2 pk;
    pk.x = cvtpk_bf16(p[n][0], p[n][1]);
    pk.y = cvtpk_bf16(p[n][2], p[n][3]);
    *(uint2*)(lp + rowB + (((n << 5) + (g << 3)) ^ xsw)) = pk;
  }

  // O += P V ; lacc += P * ones (row-sum via matrix pipe)
  bf16x8 pf0 = *(const bf16x8*)(lp + rowB + x0);
  bf16x8 pf1 = *(const bf16x8*)(lp + rowB + x1);
  const bf16x8 ones = {0x3F80, 0x3F80, 0x3F80, 0x3F80,
                       0x3F80, 0x3F80, 0x3F80, 0x3F80};  // bf16 1.0
  __builtin_amdgcn_s_setprio(1);
  lacc = __builtin_amdgcn_mfma_f32_16x16x32_bf16(pf0, ones, lacc, 0, 0, 0);
  lacc = __builtin_amdgcn_mfma_f32_16x16x32_bf16(pf1, ones, lacc, 0, 0, 0);
#pragma unroll
  for (int dt = 0; dt < 4; ++dt) {
    bf16x8 vf0 = *(const bf16x8*)(lv0 + VOFF + (dt << 11) + rowB + x0);
    oacc[dt] = __builtin_amdgcn_mfma_f32_16x16x32_bf16(pf0, vf0, oacc[dt], 0, 0, 0);
    bf16x8 vf1 = *(const bf16x8*)(lv0 + VOFF + (dt << 11) + rowB + x1);
    oacc[dt] = __builtin_amdgcn_mfma_f32_16x16x32_bf16(pf1, vf1, oacc[dt], 0, 0, 0);
  }
  __builtin_amdgcn_s_setprio(0);
}

// ---------------- fused flash attention, swapped-QK^T, 2-phase dbuf -------
// block = 4 waves, 64 Q rows (16/wave); 16 KV tiles of 64, unrolled x2 with
// compile-time buffer offsets. 40KB LDS -> 4 blocks/CU (occupancy is the
// binding resource: R9's 3-ring at 56KB cost 4->2 blocks/CU and regressed).
__global__ __launch_bounds__(256) void attn_k(const u16* __restrict__ qkv,
                                              const u16* __restrict__ vT,
                                              u16* __restrict__ ob) {
  __shared__ u16 Ks[2][64 * 64];   // [buf][kv][d] rows 128B, swz ^((kv&7)<<4)
  __shared__ u16 Vt[2][64 * 64];   // [buf][d][kv] rows 128B, swz ^((d&7)<<4)
  __shared__ u16 Ps[4][16 * 64];   // per-wave P [q][kv], swz ^((q&7)<<4)
  const int t = threadIdx.x;
  const int lane = t & 63;
  const int w = t >> 6;
  const int g = lane >> 4;
  const int q15 = lane & 15;

  // XCD-aware swizzle: 1536 blocks = 8 XCDs x 12 heads x 16 q-tiles
  const int orig = blockIdx.x;
  const int sub = orig >> 3;
  const int hb = (orig & 7) * 12 + (sub >> 4);
  const int qt = sub & 15;
  const int b = hb / H_;
  const int h = hb - b * H_;
  const int rowbase = b * N_;
  const int qcol = h * DH_;
  const int kcol = DIM_ + qcol;

  // Q fragment (B-operand: col=q15, k=d=g*8+j+32ks), pre-scaled by SCL_
  bf16x8 qf[2];
  {
    const int qrow = rowbase + (qt << 6) + (w << 4) + q15;
    const u16* src = qkv + (size_t)qrow * NQKV_ + qcol + (g << 3);
#pragma unroll
    for (int ks = 0; ks < 2; ++ks) {
      u16x8 raw = *(const u16x8*)(src + ks * 32);
      bf16x8 o;
#pragma unroll
      for (int j = 0; j < 8; ++j) o[j] = (short)f2bf(bf2f(raw[j]) * SCL_);
      qf[ks] = o;
    }
  }

  float mrow = -1e30f;
  f32x4 lacc = (f32x4){0.f, 0.f, 0.f, 0.f};
  f32x4 oacc[4];
#pragma unroll
  for (int d = 0; d < 4; ++d) oacc[d] = (f32x4){0.f, 0.f, 0.f, 0.f};

  // staging: thread t owns LDS bytes t*16 (rows 0..31) and (t+256)*16
  // (rows 32..63); source chunk pre-swizzled: c' = c ^ (row&7)  (rule #21).
  const int sr = t >> 3;
  const int c8 = t & 7;
  const int loff0 = t << 4, loff1 = (t + 256) << 4;
  const u16* pk0 = qkv + (size_t)(rowbase + sr) * NQKV_ + kcol + ((c8 ^ (sr & 7)) << 3);
  const u16* pk1 = qkv + (size_t)(rowbase + sr + 32) * NQKV_ + kcol + ((c8 ^ (sr & 7)) << 3);
  const u16* pv0 = vT + (((size_t)(hb * 64 + sr)) << 10) + ((c8 ^ (sr & 7)) << 3);
  const u16* pv1 = vT + (((size_t)(hb * 64 + sr + 32)) << 10) + ((c8 ^ (sr & 7)) << 3);
  char* lk0 = (char*)Ks;   // buffer stride 8192 B
  char* lv0 = (char*)Vt;
  char* lp = (char*)Ps + (w << 11);

#define ASTAGE(BUFO)                                       \
  do {                                                     \
    async16(pk0, lk0 + (BUFO) + loff0);                    \
    async16(pk1, lk0 + (BUFO) + loff1);                    \
    async16(pv0, lv0 + (BUFO) + loff0);                    \
    async16(pv1, lv0 + (BUFO) + loff1);                    \
    pk0 += (size_t)64 * NQKV_; pk1 += (size_t)64 * NQKV_;  \
    pv0 += 64; pv1 += 64;                                  \
  } while (0)

  // loop-invariant read offsets (note: kv&7 == d&7 == q15&7 across uses)
  const int rowB = q15 << 7;
  const int xsw = (q15 & 7) << 4;
  const int x0 = (g << 4) ^ xsw;
  const int x1 = (64 + (g << 4)) ^ xsw;

  ASTAGE(0);  // tile 0 -> buf0
  WAIT0_BAR();
  for (int kvt = 0; kvt < 16; kvt += 2) {
    // phase 0: compute buf0 (tile kvt), prefetch tile kvt+1 -> buf1
    ASTAGE(8192);
    attn_tile<0, 0>(lk0, lv0, lp, qf, oacc, lacc, mrow, rowB, xsw, x0, x1, g);
    WAIT0_BAR();
    // phase 1: compute buf1 (tile kvt+1), prefetch tile kvt+2 -> buf0
    if (kvt < 14) ASTAGE(0);
    attn_tile<8192, 8192>(lk0, lv0, lp, qf, oacc, lacc, mrow, rowB, xsw, x0, x1, g);
    WAIT0_BAR();
  }
#undef ASTAGE

  // epilogue: normalize (lacc[j] = denom for row g*4+j -- no shuffles), write
  const int orow0 = rowbase + (qt << 6) + (w << 4) + (g << 2);
#pragma unroll
  for (int dt = 0; dt < 4; ++dt) {
    int col = qcol + (dt << 4) + q15;
#pragma unroll
    for (int j = 0; j < 4; ++j)
      ob[(size_t)(orow0 + j) * DIM_ + col] = f2bf(oacc[dt][j] / lacc[j]);
  }
}

// ---------------- launch ----------------
extern "C" void kernel_launch(void* const* d_in, const int* in_sizes, int n_in,
                              void* d_out, int out_size, void* d_ws, size_t ws_size,
                              hipStream_t stream) {
  const float* x = (const float*)d_in[0];
  const float* w_qkv = (const float*)d_in[1];
  const float* w_out = (const float*)d_in[2];
  const float* b_out = (const float*)d_in[3];

  u16* xb = (u16*)d_ws;                               // 8192*768
  u16* wqkvb = xb + (size_t)M_ * DIM_;                // 2304*768
  u16* woutb = wqkvb + (size_t)NQKV_ * DIM_;          // 768*768
  u16* qkvb = woutb + (size_t)DIM_ * DIM_;            // 8192*2304 (V third unused)
  u16* obuf = qkvb + (size_t)M_ * NQKV_;              // 8192*768
  u16* vT = obuf + (size_t)M_ * DIM_;                 // 96*64*1024 transposed V
  // total ~80.2 MB of workspace

  {
    int n4 = M_ * DIM_ / 4;
    cast_bf16_k<<<(n4 + 255) / 256, 256, 0, stream>>>(x, xb, n4);
  }
  {
    int n4 = NQKV_ * DIM_ / 4;
    cast_bf16_k<<<(n4 + 255) / 256, 256, 0, stream>>>(w_qkv, wqkvb, n4);
  }
  {
    int n4 = DIM_ * DIM_ / 4;
    cast_bf16_k<<<(n4 + 255) / 256, 256, 0, stream>>>(w_out, woutb, n4);
  }

  // 1D grids with in-kernel XCD y-panel swizzle (nby=64=8x8 exactly)
  gemm_bt_k<true, false, true><<<dim3((NQKV_ / 128) * (M_ / 128)), 256, 0, stream>>>(
      xb, wqkvb, (void*)qkvb, nullptr, DIM_, NQKV_, vT);

  attn_k<<<dim3(B_ * H_ * 16), 256, 0, stream>>>(qkvb, vT, obuf);

  gemm_bt_k<false, true, false><<<dim3((DIM_ / 128) * (M_ / 128)), 256, 0, stream>>>(
      obuf, woutb, d_out, b_out, DIM_, DIM_, nullptr);
}